// Round 1
// baseline (810.250 us; speedup 1.0000x reference)
//
#include <hip/hip_runtime.h>
#include <hip/hip_bf16.h>
#include <math.h>

#define B_ 64
#define L_ 512
#define DQ_ 2048
#define H_ 128
#define K_ 128
#define DC_ 512
#define DCQ_ 1536
#define R_ 64

// log2(10000)
#define LOG2_1E4 13.287712379549449f

// ---------------- RoPE sin/cos tables: [L][DC] each ----------------
__global__ void rope_table_kernel(float* __restrict__ sin_t, float* __restrict__ cos_t) {
    int l = blockIdx.x;        // 0..511
    int d = threadIdx.x;       // 0..255; handles d and d+256
    float if1 = exp2f(-(float)(2 * (d >> 1)) * (LOG2_1E4 / 512.0f));
    float if2 = exp2f(-(float)(2 * ((d + 256) >> 1)) * (LOG2_1E4 / 512.0f));
    float a1 = (float)l * if1, a2 = (float)l * if2;
    float s1, c1, s2, c2;
    sincosf(a1, &s1, &c1);
    sincosf(a2, &s2, &c2);
    sin_t[l * DC_ + d] = s1;       cos_t[l * DC_ + d] = c1;
    sin_t[l * DC_ + d + 256] = s2; cos_t[l * DC_ + d + 256] = c2;
}

// ---------------- RoPE apply + kv_sum over L ----------------
// grid: B*8 blocks (8 l-chunks of 64), 256 threads; thread t handles d=t and d=t+256
__global__ void rope_kernel(const float* __restrict__ kv_c,
                            const float* __restrict__ sin_t, const float* __restrict__ cos_t,
                            float* __restrict__ kv, float* __restrict__ kv_sum) {
    int b = blockIdx.x >> 3;
    int l0 = (blockIdx.x & 7) * 64;
    int d = threadIdx.x;
    const float* base = kv_c + (size_t)b * L_ * DC_;
    float* obase = kv + (size_t)b * L_ * DC_;
    float s_lo = 0.f, s_hi = 0.f;
    for (int l = l0; l < l0 + 64; ++l) {
        float x1 = base[l * DC_ + d];
        float x2 = base[l * DC_ + d + 256];
        float c1 = cos_t[l * DC_ + d],       s1 = sin_t[l * DC_ + d];
        float c2 = cos_t[l * DC_ + d + 256], s2 = sin_t[l * DC_ + d + 256];
        float y1 = fmaf(x1, c1, -x2 * s1);   // rot[d] = -x[d+256] for d<256
        float y2 = fmaf(x2, c2,  x1 * s2);   // rot[d+256] = x[d]
        obase[l * DC_ + d] = y1;
        obase[l * DC_ + d + 256] = y2;
        s_lo += y1; s_hi += y2;
    }
    atomicAdd(&kv_sum[b * DC_ + d], s_lo);
    atomicAdd(&kv_sum[b * DC_ + d + 256], s_hi);
}

// ---------------- generic tiled fp32 GEMM ----------------
// C[m,n] (+)= sum_k A[m,k] * B(n,k)
// BT=true : B element at n*ldb + k   (B is [N,K] row-major, "NT")
// BT=false: B element at k*ldb + n   (B is [K,N] row-major, "NN")
// batched via z: A += asb*z, B += bsb*z, C += csb*z
// grid: (N/64, (M/64)*ksplit, batch). ksplit>1 -> atomicAdd into pre-zeroed C.
template<bool BT>
__global__ __launch_bounds__(256)
void gemm_kernel(const float* __restrict__ A, const float* __restrict__ Bm,
                 float* __restrict__ C,
                 int M, int N, int K,
                 long asb, long bsb, long csb,
                 int lda, int ldb, int ldc,
                 int ksplit)
{
    const int BM = 64, BN = 64, BK = 32;
    __shared__ float As[BK][BM + 4];
    __shared__ float Bs[BK][BN + 4];
    int z = blockIdx.z;
    int mtiles = M / BM;
    int mt = blockIdx.y % mtiles;
    int ks = blockIdx.y / mtiles;
    int n0 = blockIdx.x * BN;
    int m0 = mt * BM;
    int kchunk = K / ksplit;
    int k_begin = ks * kchunk;
    int k_end = k_begin + kchunk;
    const float* Ab = A + asb * z;
    const float* Bb = Bm + bsb * z;
    float* Cb = C + csb * z;
    int tid = threadIdx.x;
    int tn = tid & 15, tm = tid >> 4;

    float acc[4][4] = {};

    for (int k0 = k_begin; k0 < k_end; k0 += BK) {
        // A tile -> As[k][m], transposed store. float4 over k.
        {
            int kq = (tid & 7) * 4;
            int m = tid >> 3;   // 0..31
#pragma unroll
            for (int p = 0; p < 2; p++) {
                float4 v = *(const float4*)&Ab[(size_t)(m0 + m + p * 32) * lda + k0 + kq];
                As[kq + 0][m + p * 32] = v.x;
                As[kq + 1][m + p * 32] = v.y;
                As[kq + 2][m + p * 32] = v.z;
                As[kq + 3][m + p * 32] = v.w;
            }
        }
        if (BT) {
            int kq = (tid & 7) * 4;
            int n = tid >> 3;
#pragma unroll
            for (int p = 0; p < 2; p++) {
                float4 v = *(const float4*)&Bb[(size_t)(n0 + n + p * 32) * ldb + k0 + kq];
                Bs[kq + 0][n + p * 32] = v.x;
                Bs[kq + 1][n + p * 32] = v.y;
                Bs[kq + 2][n + p * 32] = v.z;
                Bs[kq + 3][n + p * 32] = v.w;
            }
        } else {
            int nq = (tid & 15) * 4;
            int k = tid >> 4;   // 0..15
#pragma unroll
            for (int p = 0; p < 2; p++) {
                float4 v = *(const float4*)&Bb[(size_t)(k0 + k + p * 16) * ldb + n0 + nq];
                *(float4*)&Bs[k + p * 16][nq] = v;
            }
        }
        __syncthreads();
#pragma unroll
        for (int kk = 0; kk < BK; kk++) {
            float4 a = *(const float4*)&As[kk][tm * 4];
            float4 b = *(const float4*)&Bs[kk][tn * 4];
            float av[4] = {a.x, a.y, a.z, a.w};
            float bv[4] = {b.x, b.y, b.z, b.w};
#pragma unroll
            for (int i = 0; i < 4; i++)
#pragma unroll
                for (int j = 0; j < 4; j++)
                    acc[i][j] = fmaf(av[i], bv[j], acc[i][j]);
        }
        __syncthreads();
    }

    if (ksplit == 1) {
#pragma unroll
        for (int i = 0; i < 4; i++) {
            float4 v = {acc[i][0], acc[i][1], acc[i][2], acc[i][3]};
            *(float4*)&Cb[(size_t)(m0 + tm * 4 + i) * ldc + n0 + tn * 4] = v;
        }
    } else {
#pragma unroll
        for (int i = 0; i < 4; i++)
#pragma unroll
            for (int j = 0; j < 4; j++)
                atomicAdd(&Cb[(size_t)(m0 + tm * 4 + i) * ldc + n0 + tn * 4 + j], acc[i][j]);
    }
}

// ---------------- scale by kv_sum + softmax over d (512) ----------------
// grid: B*H blocks, 256 threads; thread t handles d=t and d=t+256. In-place ok.
__global__ void softmax_kernel(const float* __restrict__ s2, const float* __restrict__ kv_sum,
                               float* __restrict__ attn) {
    int b = blockIdx.x >> 7;
    int h = blockIdx.x & 127;
    int d = threadIdx.x;
    const float* srow = s2 + ((size_t)b * H_ + h) * DC_;
    float v1 = srow[d] * kv_sum[b * DC_ + d];
    float v2 = srow[d + 256] * kv_sum[b * DC_ + d + 256];

    __shared__ float red[8];
    int lane = threadIdx.x & 63, wid = threadIdx.x >> 6;

    float m = fmaxf(v1, v2);
    for (int off = 32; off; off >>= 1) m = fmaxf(m, __shfl_down(m, off));
    if (lane == 0) red[wid] = m;
    __syncthreads();
    if (threadIdx.x == 0) {
        float mm = red[0];
        for (int i = 1; i < 4; i++) mm = fmaxf(mm, red[i]);
        red[4] = mm;
    }
    __syncthreads();
    m = red[4];

    float e1 = expf(v1 - m), e2 = expf(v2 - m);
    float s = e1 + e2;
    for (int off = 32; off; off >>= 1) s += __shfl_down(s, off);
    if (lane == 0) red[wid] = s;
    __syncthreads();
    if (threadIdx.x == 0) {
        float ss = 0.f;
        for (int i = 0; i < 4; i++) ss += red[i];
        red[5] = ss;
    }
    __syncthreads();
    float inv = 1.0f / red[5];

    float* arow = attn + ((size_t)b * H_ + h) * DC_;
    arow[d] = e1 * inv;
    arow[d + 256] = e2 * inv;
}

extern "C" void kernel_launch(void* const* d_in, const int* in_sizes, int n_in,
                              void* d_out, int out_size, void* d_ws, size_t ws_size,
                              hipStream_t stream) {
    const float* hidden_q   = (const float*)d_in[0];  // [64, 2048]
    const float* kv_c       = (const float*)d_in[1];  // [64, 512, 512]
    const float* q_proj_w   = (const float*)d_in[2];  // [16384, 2048]
    const float* w_kc_q     = (const float*)d_in[3];  // [128, 128, 1536]
    const float* w_kc_kv    = (const float*)d_in[4];  // [128, 128, 512]
    const float* W_qr       = (const float*)d_in[5];  // [128, 1536, 64]
    const float* W_kr       = (const float*)d_in[6];  // [128, 512, 64]
    const float* out_proj_w = (const float*)d_in[7];  // [2048, 16384]
    float* out = (float*)d_out;                       // [64, 2048]
    float* ws = (float*)d_ws;

    // workspace layout (float offsets)
    float* sin_t   = ws;                 // 262144
    float* cos_t   = ws + 262144;        // 262144
    float* kv      = ws + 524288;        // 16777216
    float* kv_sum  = ws + 17301504;      // 32768
    float* q_hk    = ws + 17334272;      // 1048576
    float* q_big   = ws + 18382848;      // 12582912
    float* q_r     = ws + 30965760;      // 524288
    float* s2      = ws + 31490048;      // 4194304  (becomes attn in place)
    float* ctx_c   = ws + 35684352;      // 4194304
    float* ctx_lat = ws + 39878656;      // 1048576

    // zero split-K accumulation targets + kv_sum
    hipMemsetAsync(kv_sum,  0, 32768u * 4, stream);
    hipMemsetAsync(q_hk,    0, 1048576u * 4, stream);
    hipMemsetAsync(q_r,     0, 524288u * 4, stream);
    hipMemsetAsync(ctx_lat, 0, 1048576u * 4, stream);
    hipMemsetAsync(out,     0, (size_t)B_ * DQ_ * 4, stream);

    // 1. RoPE tables + apply + kv_sum
    rope_table_kernel<<<512, 256, 0, stream>>>(sin_t, cos_t);
    rope_kernel<<<B_ * 8, 256, 0, stream>>>(kv_c, sin_t, cos_t, kv, kv_sum);

    // 2. q_hk = hidden_q @ q_proj_w^T   [64,16384], K=2048, split-K 2
    gemm_kernel<true><<<dim3(16384 / 64, 1 * 2, 1), 256, 0, stream>>>(
        hidden_q, q_proj_w, q_hk, 64, 16384, 2048,
        0, 0, 0, DQ_, DQ_, H_ * K_, 2);

    // 3. q_big[b,h,q] = sum_k q_hk[b,h,k] w_kc_q[h,k,q]   batch=H, [64,1536], K=128
    gemm_kernel<false><<<dim3(1536 / 64, 1, H_), 256, 0, stream>>>(
        q_hk, w_kc_q, q_big, 64, 1536, 128,
        (long)K_, (long)K_ * DCQ_, (long)DCQ_, H_ * K_, DCQ_, H_ * DCQ_, 1);

    // 4. q_r[b,h,r] = sum_q q_big[b,h,q] W_qr[h,q,r]   batch=H, [64,64], K=1536, split-K 4
    gemm_kernel<false><<<dim3(1, 4, H_), 256, 0, stream>>>(
        q_big, W_qr, q_r, 64, 64, 1536,
        (long)DCQ_, (long)DCQ_ * R_, (long)R_, H_ * DCQ_, R_, H_ * R_, 4);

    // 5. s2[b,h,d] = sum_r q_r[b,h,r] W_kr[h,d,r]   batch=H, [64,512], K=64 (NT)
    gemm_kernel<true><<<dim3(512 / 64, 1, H_), 256, 0, stream>>>(
        q_r, W_kr, s2, 64, 512, 64,
        (long)R_, (long)DC_ * R_, (long)DC_, H_ * R_, R_, H_ * DC_, 1);

    // 6. attn = softmax(kv_sum * s2) over d, in place
    softmax_kernel<<<B_ * H_, 256, 0, stream>>>(s2, kv_sum, s2);

    // 7. ctx_c[b,h,d] = sum_j attn[b,h,j] kv[b,j,d]   batch=B, M=128(H), [128,512], K=512
    gemm_kernel<false><<<dim3(512 / 64, 2, B_), 256, 0, stream>>>(
        s2, kv, ctx_c, H_, 512, 512,
        (long)H_ * DC_, (long)L_ * DC_, (long)H_ * DC_, DC_, DC_, DC_, 1);

    // 8. ctx_lat[b,h*K+k] = sum_d ctx_c[b,h,d] w_kc_kv[h,k,d]  batch=H, [64,128], K=512 (NT), split-K 4
    gemm_kernel<true><<<dim3(128 / 64, 4, H_), 256, 0, stream>>>(
        ctx_c, w_kc_kv, ctx_lat, 64, 128, 512,
        (long)DC_, (long)K_ * DC_, (long)K_, H_ * DC_, DC_, H_ * K_, 4);

    // 9. out = ctx_lat @ out_proj_w^T   [64,2048], K=16384 (NT), split-K 16
    gemm_kernel<true><<<dim3(2048 / 64, 16, 1), 256, 0, stream>>>(
        ctx_lat, out_proj_w, out, 64, 2048, 16384,
        0, 0, 0, H_ * K_, H_ * K_, DQ_, 16);
}

// Round 2
// 716.212 us; speedup vs baseline: 1.1313x; 1.1313x over previous
//
#include <hip/hip_runtime.h>
#include <hip/hip_bf16.h>
#include <math.h>

#define B_ 64
#define L_ 512
#define DQ_ 2048
#define H_ 128
#define K_ 128
#define DC_ 512
#define DCQ_ 1536
#define R_ 64

// log2(10000)
#define LOG2_1E4 13.287712379549449f

typedef __attribute__((ext_vector_type(8))) short bf16x8;
typedef __attribute__((ext_vector_type(4))) float f32x4;

__device__ __forceinline__ short f2bf(float f) {
    union { float f; unsigned u; } v; v.f = f;
    unsigned r = v.u + 0x7fffu + ((v.u >> 16) & 1u);   // RNE
    return (short)(r >> 16);
}

__device__ __forceinline__ bf16x8 cvt8(float4 a, float4 b) {
    bf16x8 r;
    r[0] = f2bf(a.x); r[1] = f2bf(a.y); r[2] = f2bf(a.z); r[3] = f2bf(a.w);
    r[4] = f2bf(b.x); r[5] = f2bf(b.y); r[6] = f2bf(b.z); r[7] = f2bf(b.w);
    return r;
}

// ---------------- RoPE sin/cos tables: [L][DC] each ----------------
__global__ void rope_table_kernel(float* __restrict__ sin_t, float* __restrict__ cos_t) {
    int l = blockIdx.x;
    int d = threadIdx.x;
    float if1 = exp2f(-(float)(2 * (d >> 1)) * (LOG2_1E4 / 512.0f));
    float if2 = exp2f(-(float)(2 * ((d + 256) >> 1)) * (LOG2_1E4 / 512.0f));
    float a1 = (float)l * if1, a2 = (float)l * if2;
    float s1, c1, s2, c2;
    sincosf(a1, &s1, &c1);
    sincosf(a2, &s2, &c2);
    sin_t[l * DC_ + d] = s1;       cos_t[l * DC_ + d] = c1;
    sin_t[l * DC_ + d + 256] = s2; cos_t[l * DC_ + d + 256] = c2;
}

// ---------------- RoPE apply + kv_sum over L ----------------
__global__ void rope_kernel(const float* __restrict__ kv_c,
                            const float* __restrict__ sin_t, const float* __restrict__ cos_t,
                            float* __restrict__ kv, float* __restrict__ kv_sum) {
    int b = blockIdx.x >> 3;
    int l0 = (blockIdx.x & 7) * 64;
    int d = threadIdx.x;
    const float* base = kv_c + (size_t)b * L_ * DC_;
    float* obase = kv + (size_t)b * L_ * DC_;
    float s_lo = 0.f, s_hi = 0.f;
    for (int l = l0; l < l0 + 64; ++l) {
        float x1 = base[l * DC_ + d];
        float x2 = base[l * DC_ + d + 256];
        float c1 = cos_t[l * DC_ + d],       s1 = sin_t[l * DC_ + d];
        float c2 = cos_t[l * DC_ + d + 256], s2 = sin_t[l * DC_ + d + 256];
        float y1 = fmaf(x1, c1, -x2 * s1);
        float y2 = fmaf(x2, c2,  x1 * s2);
        obase[l * DC_ + d] = y1;
        obase[l * DC_ + d + 256] = y2;
        s_lo += y1; s_hi += y2;
    }
    atomicAdd(&kv_sum[b * DC_ + d], s_lo);
    atomicAdd(&kv_sum[b * DC_ + d + 256], s_hi);
}

// ---------------- barrier-free MFMA GEMM, bf16-in-register ----------------
// C[m,n] (+)= sum_k A[m,k] * B(n,k)
// BT=true : B element at n*ldb + k   ("NT", k contiguous)
// BT=false: B element at k*ldb + n   ("NN", n contiguous)
// grid: (N/64, (M/64)*ksplit, batch). Block = 256 = 4 waves; wave w owns
// n-cols [n0+16w, n0+16w+16), all 64 m-rows (4 MFMA m-tiles of 16).
// MFMA 16x16x32_bf16 frag layouts:
//   A: lane holds A[m = lane&15][k = (lane>>4)*8 + j], j=0..7
//   B: lane holds B[n = lane&15][k = (lane>>4)*8 + j]
//   C/D: lane,reg -> row = (lane>>4)*4 + reg, col = lane&15
template<bool BT>
__global__ __launch_bounds__(256)
void gemm_mfma(const float* __restrict__ A, const float* __restrict__ Bm,
               float* __restrict__ C,
               int M, int N, int K,
               long asb, long bsb, long csb,
               int lda, int ldb, int ldc,
               int ksplit)
{
    int z = blockIdx.z;
    int mtiles = M >> 6;
    int mt = blockIdx.y % mtiles;
    int ks = blockIdx.y / mtiles;
    int n0 = blockIdx.x * 64;
    int m0 = mt * 64;
    int kchunk = K / ksplit;
    int k_begin = ks * kchunk, k_end = k_begin + kchunk;
    const float* Ab = A + asb * z;
    const float* Bb = Bm + bsb * z;
    float* Cb = C + csb * z;

    int lane = threadIdx.x & 63;
    int w = threadIdx.x >> 6;
    int l15 = lane & 15;
    int kg = lane >> 4;              // 0..3
    int arow0 = m0 + l15;
    int nb = n0 + w * 16 + l15;      // this lane's B n-index

    f32x4 acc[4] = {{0,0,0,0},{0,0,0,0},{0,0,0,0},{0,0,0,0}};

#pragma unroll 2
    for (int k0 = k_begin; k0 < k_end; k0 += 32) {
        int kb = k0 + kg * 8;
        bf16x8 af[4], bfv;
#pragma unroll
        for (int t = 0; t < 4; t++) {
            const float* p = Ab + (size_t)(arow0 + t * 16) * lda + kb;
            float4 x = *(const float4*)p;
            float4 y = *(const float4*)(p + 4);
            af[t] = cvt8(x, y);
        }
        if (BT) {
            const float* p = Bb + (size_t)nb * ldb + kb;
            float4 x = *(const float4*)p;
            float4 y = *(const float4*)(p + 4);
            bfv = cvt8(x, y);
        } else {
            const float* p = Bb + (size_t)kb * ldb + nb;
            float tmp[8];
#pragma unroll
            for (int j = 0; j < 8; j++) tmp[j] = p[(size_t)j * ldb];
#pragma unroll
            for (int j = 0; j < 8; j++) bfv[j] = f2bf(tmp[j]);
        }
#pragma unroll
        for (int t = 0; t < 4; t++)
            acc[t] = __builtin_amdgcn_mfma_f32_16x16x32_bf16(af[t], bfv, acc[t], 0, 0, 0);
    }

    int crow0 = m0 + kg * 4;
    int ccol = n0 + w * 16 + l15;
    if (ksplit == 1) {
#pragma unroll
        for (int t = 0; t < 4; t++)
#pragma unroll
            for (int r = 0; r < 4; r++)
                Cb[(size_t)(crow0 + t * 16 + r) * ldc + ccol] = acc[t][r];
    } else {
#pragma unroll
        for (int t = 0; t < 4; t++)
#pragma unroll
            for (int r = 0; r < 4; r++)
                atomicAdd(&Cb[(size_t)(crow0 + t * 16 + r) * ldc + ccol], acc[t][r]);
    }
}

// ---------------- scale by kv_sum + softmax over d (512) ----------------
__global__ void softmax_kernel(const float* __restrict__ s2, const float* __restrict__ kv_sum,
                               float* __restrict__ attn) {
    int b = blockIdx.x >> 7;
    int h = blockIdx.x & 127;
    int d = threadIdx.x;
    const float* srow = s2 + ((size_t)b * H_ + h) * DC_;
    float v1 = srow[d] * kv_sum[b * DC_ + d];
    float v2 = srow[d + 256] * kv_sum[b * DC_ + d + 256];

    __shared__ float red[8];
    int lane = threadIdx.x & 63, wid = threadIdx.x >> 6;

    float m = fmaxf(v1, v2);
    for (int off = 32; off; off >>= 1) m = fmaxf(m, __shfl_down(m, off));
    if (lane == 0) red[wid] = m;
    __syncthreads();
    if (threadIdx.x == 0) {
        float mm = red[0];
        for (int i = 1; i < 4; i++) mm = fmaxf(mm, red[i]);
        red[4] = mm;
    }
    __syncthreads();
    m = red[4];

    float e1 = expf(v1 - m), e2 = expf(v2 - m);
    float s = e1 + e2;
    for (int off = 32; off; off >>= 1) s += __shfl_down(s, off);
    if (lane == 0) red[wid] = s;
    __syncthreads();
    if (threadIdx.x == 0) {
        float ss = 0.f;
        for (int i = 0; i < 4; i++) ss += red[i];
        red[5] = ss;
    }
    __syncthreads();
    float inv = 1.0f / red[5];

    float* arow = attn + ((size_t)b * H_ + h) * DC_;
    arow[d] = e1 * inv;
    arow[d + 256] = e2 * inv;
}

extern "C" void kernel_launch(void* const* d_in, const int* in_sizes, int n_in,
                              void* d_out, int out_size, void* d_ws, size_t ws_size,
                              hipStream_t stream) {
    const float* hidden_q   = (const float*)d_in[0];  // [64, 2048]
    const float* kv_c       = (const float*)d_in[1];  // [64, 512, 512]
    const float* q_proj_w   = (const float*)d_in[2];  // [16384, 2048]
    const float* w_kc_q     = (const float*)d_in[3];  // [128, 128, 1536]
    const float* w_kc_kv    = (const float*)d_in[4];  // [128, 128, 512]
    const float* W_qr       = (const float*)d_in[5];  // [128, 1536, 64]
    const float* W_kr       = (const float*)d_in[6];  // [128, 512, 64]
    const float* out_proj_w = (const float*)d_in[7];  // [2048, 16384]
    float* out = (float*)d_out;                       // [64, 2048]
    float* ws = (float*)d_ws;

    // workspace layout (float offsets)
    float* sin_t   = ws;                 //   262144
    float* cos_t   = ws + 262144;        //   262144
    float* kv      = ws + 524288;        // 16777216
    float* kv_sum  = ws + 17301504;      //    32768
    float* q_hk    = ws + 17334272;      //  1048576  [64,16384]
    float* W_comb  = ws + 18382848;      //  1048576  [128,128,64]
    float* q_r     = ws + 19431424;      //   524288  [64,128,64]
    float* s2      = ws + 19955712;      //  4194304  [64,128,512] (attn in place)
    float* ctx_c   = ws + 24150016;      //  4194304  [64,128,512]
    float* ctx_lat = ws + 28344320;      //  1048576  [64,16384]

    // zero atomic-accumulation targets
    hipMemsetAsync(kv_sum, 0, 32768u * 4, stream);
    hipMemsetAsync(q_hk,   0, 1048576u * 4, stream);
    hipMemsetAsync(out,    0, (size_t)B_ * DQ_ * 4, stream);

    // 1. RoPE tables + apply + kv_sum
    rope_table_kernel<<<512, 256, 0, stream>>>(sin_t, cos_t);
    rope_kernel<<<B_ * 8, 256, 0, stream>>>(kv_c, sin_t, cos_t, kv, kv_sum);

    // 2. W_comb[h] = w_kc_q[h] @ W_qr[h]   M=128(kk), N=64(r), K=1536(q), batch H
    gemm_mfma<false><<<dim3(1, 2, H_), 256, 0, stream>>>(
        w_kc_q, W_qr, W_comb, 128, 64, 1536,
        (long)K_ * DCQ_, (long)DCQ_ * R_, (long)K_ * R_,
        DCQ_, R_, R_, 1);

    // 3. q_hk = hidden_q @ q_proj_w^T   M=64, N=16384, K=2048, split-K 2
    gemm_mfma<true><<<dim3(256, 2, 1), 256, 0, stream>>>(
        hidden_q, q_proj_w, q_hk, 64, 16384, 2048,
        0, 0, 0, DQ_, DQ_, H_ * K_, 2);

    // 4. q_r[b,h,r] = q_hk[b,h,:] @ W_comb[h]   M=64(b), N=64(r), K=128(kk), batch H
    gemm_mfma<false><<<dim3(1, 1, H_), 256, 0, stream>>>(
        q_hk, W_comb, q_r, 64, 64, 128,
        (long)K_, (long)K_ * R_, (long)R_,
        H_ * K_, R_, H_ * R_, 1);

    // 5. s2[b,h,d] = q_r[b,h,:] @ W_kr[h]^T   M=64(b), N=512(d), K=64(r), batch H (NT)
    gemm_mfma<true><<<dim3(8, 1, H_), 256, 0, stream>>>(
        q_r, W_kr, s2, 64, 512, 64,
        (long)R_, (long)DC_ * R_, (long)DC_,
        H_ * R_, R_, H_ * DC_, 1);

    // 6. attn = softmax(kv_sum * s2) over d, in place
    softmax_kernel<<<B_ * H_, 256, 0, stream>>>(s2, kv_sum, s2);

    // 7. ctx_c[b] = attn[b] @ kv[b]   M=128(h), N=512(d), K=512(l), batch B (NN)
    gemm_mfma<false><<<dim3(8, 2, B_), 256, 0, stream>>>(
        s2, kv, ctx_c, 128, 512, 512,
        (long)H_ * DC_, (long)L_ * DC_, (long)H_ * DC_,
        DC_, DC_, DC_, 1);

    // 8. ctx_lat[b,h*K+kk] = ctx_c[b,h,:] @ w_kc_kv[h]^T   M=64(b), N=128(kk), K=512(d), batch H (NT)
    gemm_mfma<true><<<dim3(2, 1, H_), 256, 0, stream>>>(
        ctx_c, w_kc_kv, ctx_lat, 64, 128, 512,
        (long)DC_, (long)K_ * DC_, (long)K_,
        H_ * DC_, DC_, H_ * K_, 1);

    // 9. out = ctx_lat @ out_proj_w^T   M=64, N=2048, K=16384 (NT), split-K 8
    gemm_mfma<true><<<dim3(32, 8, 1), 256, 0, stream>>>(
        ctx_lat, out_proj_w, out, 64, 2048, 16384,
        0, 0, 0, H_ * K_, H_ * K_, DQ_, 8);
}